// Round 4
// baseline (248.304 us; speedup 1.0000x reference)
//
#include <hip/hip_runtime.h>
#include <hip/hip_bf16.h>

// Problem: B=8, C=256, T=16, H=28, W=28
//   h_t = 0.5*(W @ h_{t-1} + x_t); out[:,:,0]=x0, out[:,:,t]=h_t
//
// R4: R1/R3 both drained stores every step (vmcnt(0) is FIFO: stores issued
// before the x-loads must retire first) -> ~2.1 TB/s latency-bound. Now:
// triple-buffered x slab, prefetch x_{t+2} via global_load_lds at step top,
// and a surgical `s_waitcnt vmcnt(40)` that retires exactly the 2-step-old
// x loads while leaving 2 steps of stores (and 1.5 steps of loads) in
// flight forever. h handoff keeps the lgkm-only barrier.
// Per-wave VM ops/step: [4 DMA loads][16 stores] -> at the wait, the 40
// youngest = S_{t-2}(16)+A_{t-1}(4)+S_{t-1}(16)+A_t(4); prologue vmcnt(0)
// drain makes vmcnt(40) uniformly correct from t=1.

typedef __attribute__((ext_vector_type(8))) short bf16x8;  // 8 bf16 = 4 VGPRs
typedef __attribute__((ext_vector_type(4))) float f32x4;

#define NTILES 49       // 784/16 spatial tiles per batch -> 392 blocks
#define LDSK   264      // h stride 528 B: b128 reads conflict-free
#define CSTRIDE 12544   // 16*784 elements between channels

#define AS1 __attribute__((address_space(1)))
#define AS3 __attribute__((address_space(3)))

__device__ __forceinline__ void ld_lds16(const float* g, float* l) {
    // async 16B/lane global->LDS; LDS dst = wave-uniform base + lane*16
    __builtin_amdgcn_global_load_lds((AS1 const unsigned int*)g,
                                     (AS3 unsigned int*)l, 16, 0, 0);
}

__device__ __forceinline__ int pkbf2(float a, float b) {
    __hip_bfloat162 h = __float22bfloat162_rn(make_float2(a, b));
    union { __hip_bfloat162 h2; int i; } u; u.h2 = h; return u.i;
}

__device__ __forceinline__ short f2bf(float f) {
    union { float f; unsigned u; } v; v.f = f;
    unsigned r = v.u + 0x7FFFu + ((v.u >> 16) & 1u);
    return (short)(r >> 16);
}

__global__ __launch_bounds__(256, 2)
void rcu_kernel(const float* __restrict__ in, const float* __restrict__ Wm,
                float* __restrict__ out) {
    __shared__ short hbuf[2][16][LDSK];   // h bf16, [n=16][k=256+8]: 16.9 KB
    __shared__ float xslab[3][256 * 16];  // x staging, [ch][col] fp32: 48 KB

    const int tid  = threadIdx.x;
    const int wave = tid >> 6;      // wave w owns output channels [w*64,+64)
    const int lane = tid & 63;
    const int l15  = lane & 15;     // spatial col / MFMA n
    const int quad = lane >> 4;

    const int b  = blockIdx.x / NTILES;
    const int s0 = (blockIdx.x % NTILES) * 16;

    const size_t base = (size_t)b * 256 * CSTRIDE + s0;
    const float* xin  = in  + base;
    float*       xout = out + base;

    // DMA lane map: lane L covers channel cb + L/4, cols (L&3)*4..+3 (16B)
    const int pf_c   = lane >> 2;
    const int pf_col = (lane & 3) * 4;

    // ---- W loads first (oldest in vmcnt FIFO), then x0/x1/x2 DMAs ----
    bf16x8 a_frag[4][8];            // 128 regs, reused all 15 steps
    float4 wtmp[4][8][2];
#pragma unroll
    for (int mt = 0; mt < 4; ++mt) {
        const int m = wave * 64 + mt * 16 + l15;
        const float* wrow = Wm + m * 256 + quad * 8;
#pragma unroll
        for (int ks = 0; ks < 8; ++ks) {
            wtmp[mt][ks][0] = *(const float4*)(wrow + ks * 32);
            wtmp[mt][ks][1] = *(const float4*)(wrow + ks * 32 + 4);
        }
    }
#pragma unroll
    for (int s = 0; s < 3; ++s)
#pragma unroll
        for (int i = 0; i < 4; ++i) {
            const int cb = wave * 64 + i * 16;
            ld_lds16(xin + (size_t)(cb + pf_c) * CSTRIDE + s * 784 + pf_col,
                     &xslab[s][cb * 16]);
        }
#pragma unroll
    for (int mt = 0; mt < 4; ++mt)
#pragma unroll
        for (int ks = 0; ks < 8; ++ks) {
            float4 f0 = wtmp[mt][ks][0], f1 = wtmp[mt][ks][1];
            bf16x8 a;
            a[0] = f2bf(f0.x); a[1] = f2bf(f0.y); a[2] = f2bf(f0.z); a[3] = f2bf(f0.w);
            a[4] = f2bf(f1.x); a[5] = f2bf(f1.y); a[6] = f2bf(f1.z); a[7] = f2bf(f1.w);
            a_frag[mt][ks] = a;
        }

    // full drain ONCE: x0,x1,x2 resident; makes loop's vmcnt(40) uniform
    __asm__ volatile("s_waitcnt vmcnt(0)" ::: "memory");

    // ---- init t=0: h0 = x0; copy to out; stage hbuf[0] ----
#pragma unroll
    for (int mt = 0; mt < 4; ++mt) {
        const int c0 = wave * 64 + mt * 16 + quad * 4;
        float v[4];
#pragma unroll
        for (int r = 0; r < 4; ++r) {
            v[r] = xslab[0][(c0 + r) * 16 + l15];
            xout[(size_t)(c0 + r) * CSTRIDE + l15] = v[r];
        }
        int2 packed;
        packed.x = pkbf2(v[0], v[1]);
        packed.y = pkbf2(v[2], v[3]);
        *(int2*)&hbuf[0][l15][c0] = packed;
    }
    __asm__ volatile("s_waitcnt lgkmcnt(0)\n\ts_barrier" ::: "memory");

    float* sp = xslab[0];   // prefetch target at t: slab consumed at t-1
    float* sc = xslab[1];   // consumed this step
    float* sn = xslab[2];
    int cur = 0;
    int tof = 784;          // t*784
#pragma unroll 1
    for (int t = 1; t < 16; ++t) {
        // 1) A_t: prefetch x_{min(t+2,15)} into sp (intra-wave, no barrier)
        const int tpf = (t + 2 <= 15) ? (t + 2) * 784 : 15 * 784;
#pragma unroll
        for (int i = 0; i < 4; ++i) {
            const int cb = wave * 64 + i * 16;
            ld_lds16(xin + (size_t)(cb + pf_c) * CSTRIDE + tpf + pf_col,
                     sp + cb * 16);
        }

        // 2) h_{t-1} B-fragments: B[k][n], k = ks*32+quad*8+j, n = l15
        bf16x8 bfrag[8];
        const short* hp = &hbuf[cur][l15][quad * 8];
#pragma unroll
        for (int ks = 0; ks < 8; ++ks)
            bfrag[ks] = *(const bf16x8*)(hp + ks * 32);   // ds_read_b128

        // 3) W @ h
        f32x4 acc[4];
#pragma unroll
        for (int mt = 0; mt < 4; ++mt) {
            f32x4 a0 = {0.f, 0.f, 0.f, 0.f};
#pragma unroll
            for (int ks = 0; ks < 8; ++ks)
                a0 = __builtin_amdgcn_mfma_f32_16x16x32_bf16(a_frag[mt][ks], bfrag[ks], a0, 0, 0, 0);
            acc[mt] = a0;
        }

        // 4) retire exactly A_{t-2} (x_t); 2 steps of stores stay in flight
        __asm__ volatile("s_waitcnt vmcnt(40)" ::: "memory");

        // 5) epilogue: v = 0.5*(Wh + x_t); store out; stage h_t
        const int nxt = cur ^ 1;
#pragma unroll
        for (int mt = 0; mt < 4; ++mt) {
            const int c0 = wave * 64 + mt * 16 + quad * 4;
            float v[4];
#pragma unroll
            for (int r = 0; r < 4; ++r) {
                v[r] = 0.5f * (acc[mt][r] + sc[(c0 + r) * 16 + l15]);
                xout[(size_t)(c0 + r) * CSTRIDE + tof + l15] = v[r];
            }
            int2 packed;
            packed.x = pkbf2(v[0], v[1]);
            packed.y = pkbf2(v[2], v[3]);
            *(int2*)&hbuf[nxt][l15][c0] = packed;
        }

        // 6) h handoff: LDS-only drain; global ops stay in flight
        __asm__ volatile("s_waitcnt lgkmcnt(0)\n\ts_barrier" ::: "memory");

        float* tmp = sp; sp = sc; sc = sn; sn = tmp;
        tof += 784;
        cur = nxt;
    }
}

extern "C" void kernel_launch(void* const* d_in, const int* in_sizes, int n_in,
                              void* d_out, int out_size, void* d_ws, size_t ws_size,
                              hipStream_t stream) {
    const float* in  = (const float*)d_in[0];
    const float* Wm  = (const float*)d_in[1];
    float*       out = (float*)d_out;
    hipLaunchKernelGGL(rcu_kernel, dim3(8 * NTILES), dim3(256), 0, stream, in, Wm, out);
}